// Round 9
// baseline (2815.517 us; speedup 1.0000x reference)
//
#include <hip/hip_runtime.h>

#define NN 100000   // nodes
#define NE 1000000  // edges
#define DD 64       // dim
#define NB 4096     // batch
#define TILE 1024                       // scan tile (ints per block)
#define NTILE ((NN + TILE - 1) / TILE)  // 98

// ---------------------------------------------------------------------------
// CSR build step 1: count edges per destination AND record each edge's rank
// within its bucket (the atomic's return value). rank is stored coalesced.
// ---------------------------------------------------------------------------
__global__ __launch_bounds__(256) void k_count(
    const int* __restrict__ ei, int* __restrict__ base, int* __restrict__ rank)
{
  const int stride = gridDim.x * blockDim.x;
  for (int e = blockIdx.x * blockDim.x + threadIdx.x; e < NE; e += stride)
    rank[e] = atomicAdd(&base[ei[NE + e]], 1);
}

// ---------------------------------------------------------------------------
// Hierarchical exclusive scan of base[0..NN) (3 kernels, coalesced int4).
// ---------------------------------------------------------------------------
__global__ __launch_bounds__(256) void k_scan_part(
    const int* __restrict__ base, int* __restrict__ tilesum)
{
  __shared__ int s[256];
  const int t = threadIdx.x;
  const int i0 = blockIdx.x * TILE + t * 4;
  int4 v = make_int4(0, 0, 0, 0);
  if (i0 < NN) v = *reinterpret_cast<const int4*>(base + i0);  // NN%4==0
  s[t] = v.x + v.y + v.z + v.w;
  __syncthreads();
#pragma unroll
  for (int off = 128; off >= 1; off >>= 1) {
    if (t < off) s[t] += s[t + off];
    __syncthreads();
  }
  if (t == 0) tilesum[blockIdx.x] = s[0];
}

__global__ __launch_bounds__(128) void k_scan_tiles(
    const int* __restrict__ tilesum, int* __restrict__ tileoff)
{
  __shared__ int s[128];
  const int t = threadIdx.x;
  const int v = (t < NTILE) ? tilesum[t] : 0;
  s[t] = v;
  __syncthreads();
#pragma unroll
  for (int off = 1; off < 128; off <<= 1) {
    const int u = (t >= off) ? s[t - off] : 0;
    __syncthreads();
    s[t] += u;
    __syncthreads();
  }
  if (t < NTILE) tileoff[t] = s[t] - v;  // exclusive
}

__global__ __launch_bounds__(256) void k_scan_apply(
    int* __restrict__ base, const int* __restrict__ tileoff)
{
  __shared__ int s[256];
  const int t = threadIdx.x;
  const int i0 = blockIdx.x * TILE + t * 4;
  int4 v = make_int4(0, 0, 0, 0);
  if (i0 < NN) v = *reinterpret_cast<const int4*>(base + i0);
  const int sum = v.x + v.y + v.z + v.w;
  s[t] = sum;
  __syncthreads();
#pragma unroll
  for (int off = 1; off < 256; off <<= 1) {   // Hillis-Steele inclusive
    const int u = (t >= off) ? s[t - off] : 0;
    __syncthreads();
    s[t] += u;
    __syncthreads();
  }
  int p = s[t] - sum + tileoff[blockIdx.x];
  if (i0 < NN) {
    const int4 o = make_int4(p, p + v.x, p + v.x + v.y, p + v.x + v.y + v.z);
    *reinterpret_cast<int4*>(base + i0) = o;
  }
  if (blockIdx.x == 0 && t == 0) base[NN] = NE;
}

// ---------------------------------------------------------------------------
// CSR build step 3: bucket edges by destination, atomic-free.
// ---------------------------------------------------------------------------
__global__ __launch_bounds__(256) void k_permute(
    const int* __restrict__ ei, const float* __restrict__ ew,
    const int* __restrict__ base, const int* __restrict__ rank,
    int2* __restrict__ edata)
{
  const int stride = gridDim.x * blockDim.x;
  for (int e = blockIdx.x * blockDim.x + threadIdx.x; e < NE; e += stride) {
    const int c = ei[NE + e];
    const int slot = base[c] + rank[e];
    edata[slot] = make_int2(ei[e], __float_as_int(ew[e]));
  }
}

// ---------------------------------------------------------------------------
// Aggregation without atomics: one wave per node, lane = dim.
// ---------------------------------------------------------------------------
__global__ __launch_bounds__(256) void k_aggregate(
    const float* __restrict__ ego, const int* __restrict__ base,
    const int2* __restrict__ edata, float* __restrict__ side)
{
  const int lane = threadIdx.x & 63;
  const int gw = (blockIdx.x * 256 + threadIdx.x) >> 6;
  const int nw = (gridDim.x * 256) >> 6;
  for (int n = gw; n < NN; n += nw) {
    const int lo = base[n];
    const int hi = base[n + 1];
    float acc = 0.f;
    int j = lo;
    for (; j + 3 < hi; j += 4) {          // unroll-4 for load ILP
      const int2 a = edata[j];
      const int2 b = edata[j + 1];
      const int2 c = edata[j + 2];
      const int2 d = edata[j + 3];
      const float va = ego[(size_t)a.x * DD + lane];
      const float vb = ego[(size_t)b.x * DD + lane];
      const float vc = ego[(size_t)c.x * DD + lane];
      const float vd = ego[(size_t)d.x * DD + lane];
      acc = fmaf(va, __int_as_float(a.y), acc);
      acc = fmaf(vb, __int_as_float(b.y), acc);
      acc = fmaf(vc, __int_as_float(c.y), acc);
      acc = fmaf(vd, __int_as_float(d.y), acc);
    }
    for (; j < hi; ++j) {
      const int2 a = edata[j];
      acc = fmaf(ego[(size_t)a.x * DD + lane], __int_as_float(a.y), acc);
    }
    side[(size_t)n * DD + lane] = acc;
  }
}

// ---------------------------------------------------------------------------
// Dense update, thread-per-node: each thread holds its node's side row (s)
// and hadamard row (p) in registers; W indices are wave-uniform, so W loads
// scalarize to s_load (SGPR broadcast) — no readlanes, no per-lane W gather.
//   x = s@Wgc + p@Wbi + bias ; ego_out = leaky_relu(x, 0.2)
// j tiled by 16 (acc[16] regs, W row-slices of 16 floats = 1 s_load_dwordx16).
// Norm is NOT computed here — only sampled rows need it (see k_gather_norm).
// ---------------------------------------------------------------------------
__global__ __launch_bounds__(256) void k_update2(
    const float* __restrict__ side, const float* __restrict__ ego_in,
    float* __restrict__ ego_out,
    const float* __restrict__ Wgc, const float* __restrict__ bgc,
    const float* __restrict__ Wbi, const float* __restrict__ bbi)
{
  const int n = blockIdx.x * 256 + threadIdx.x;
  const int nc = (n < NN) ? n : (NN - 1);   // clamp loads; guard stores
  const bool act = (n < NN);

  float s[DD], p[DD];
  {
    const float4* s4 = reinterpret_cast<const float4*>(side + (size_t)nc * DD);
    const float4* e4 = reinterpret_cast<const float4*>(ego_in + (size_t)nc * DD);
#pragma unroll
    for (int q = 0; q < DD / 4; ++q) {
      const float4 sv = s4[q];
      const float4 ev = e4[q];
      s[4 * q + 0] = sv.x; s[4 * q + 1] = sv.y;
      s[4 * q + 2] = sv.z; s[4 * q + 3] = sv.w;
      p[4 * q + 0] = sv.x * ev.x; p[4 * q + 1] = sv.y * ev.y;
      p[4 * q + 2] = sv.z * ev.z; p[4 * q + 3] = sv.w * ev.w;
    }
  }
  float4* orow = reinterpret_cast<float4*>(ego_out + (size_t)nc * DD);

#pragma unroll 1            // keep jt rolled: body ~2.4K instr, fits I$
  for (int jt = 0; jt < DD / 16; ++jt) {
    const int j0 = jt * 16;
    float acc[16];
#pragma unroll
    for (int jj = 0; jj < 16; ++jj) acc[jj] = bgc[j0 + jj] + bbi[j0 + jj];
#pragma unroll
    for (int k = 0; k < DD; ++k) {        // full unroll: s[k],p[k] static
      const float sk = s[k], pk = p[k];
#pragma unroll
      for (int jj = 0; jj < 16; ++jj)
        acc[jj] = fmaf(sk, Wgc[k * DD + j0 + jj], acc[jj]);
#pragma unroll
      for (int jj = 0; jj < 16; ++jj)
        acc[jj] = fmaf(pk, Wbi[k * DD + j0 + jj], acc[jj]);
    }
    if (act) {
#pragma unroll
      for (int q = 0; q < 4; ++q) {
        const float a0 = acc[4 * q + 0], a1 = acc[4 * q + 1];
        const float a2 = acc[4 * q + 2], a3 = acc[4 * q + 3];
        float4 o;
        o.x = (a0 > 0.f) ? a0 : 0.2f * a0;
        o.y = (a1 > 0.f) ? a1 : 0.2f * a1;
        o.z = (a2 > 0.f) ? a2 : 0.2f * a2;
        o.w = (a3 > 0.f) ? a3 : 0.2f * a3;
        orow[j0 / 4 + q] = o;
      }
    }
  }
}

// ---------------------------------------------------------------------------
// Plain gather (embeds block, no normalization).
// ---------------------------------------------------------------------------
__global__ __launch_bounds__(256) void k_gather(
    const float* __restrict__ src, const int* __restrict__ users,
    const int* __restrict__ pos, const int* __restrict__ neg,
    float* __restrict__ out, int colOff)
{
  const int w = (blockIdx.x * 256 + threadIdx.x) >> 6;
  const int lane = threadIdx.x & 63;
  if (w >= 3 * NB) return;
  const int t = w / NB;
  const int i = w - t * NB;
  const int* idxp = (t == 0) ? users : ((t == 1) ? pos : neg);
  const int idx = idxp[i];
  const float v = src[(size_t)idx * DD + lane];
  const size_t o = (size_t)w * 256 + colOff + lane;
  out[o] = v;
  out[o + (size_t)3 * NB * 256] = v;
}

// ---------------------------------------------------------------------------
// Normalizing gather: L2-normalize the sampled ego row on the fly.
// Only 12,288 of 100K rows are ever read normalized — skip the rest.
// ---------------------------------------------------------------------------
__global__ __launch_bounds__(256) void k_gather_norm(
    const float* __restrict__ src, const int* __restrict__ users,
    const int* __restrict__ pos, const int* __restrict__ neg,
    float* __restrict__ out, int colOff)
{
  const int w = (blockIdx.x * 256 + threadIdx.x) >> 6;
  const int lane = threadIdx.x & 63;
  if (w >= 3 * NB) return;
  const int t = w / NB;
  const int i = w - t * NB;
  const int* idxp = (t == 0) ? users : ((t == 1) ? pos : neg);
  const int idx = idxp[i];
  const float v = src[(size_t)idx * DD + lane];
  float ss = v * v;
#pragma unroll
  for (int off = 32; off >= 1; off >>= 1) ss += __shfl_xor(ss, off);
  const float nrm = fmaxf(sqrtf(ss), 1e-12f);
  const float nv = v / nrm;
  const size_t o = (size_t)w * 256 + colOff + lane;
  out[o] = nv;
  out[o + (size_t)3 * NB * 256] = nv;
}

extern "C" void kernel_launch(void* const* d_in, const int* in_sizes, int n_in,
                              void* d_out, int out_size, void* d_ws, size_t ws_size,
                              hipStream_t stream)
{
  const float* embeds = (const float*)d_in[0];
  const float* ew     = (const float*)d_in[1];
  const float* Wgc    = (const float*)d_in[2];
  const float* bgc    = (const float*)d_in[3];
  const float* Wbi    = (const float*)d_in[4];
  const float* bbi    = (const float*)d_in[5];
  const int*   ei     = (const int*)d_in[6];
  const int*   users  = (const int*)d_in[7];
  const int*   pos    = (const int*)d_in[8];
  const int*   neg    = (const int*)d_in[9];
  float* out = (float*)d_out;

  // Workspace layout (4B units); 16B alignment holds for all accesses.
  float* side = (float*)d_ws;                     // NN*DD
  float* ego  = side + (size_t)NN * DD;           // NN*DD
  int*   base   = (int*)(ego + (size_t)NN * DD);  // NN+4 (pad)
  int*   tiles  = base + (NN + 4);                // NTILE sums + NTILE offs
  int2*  edata  = (int2*)(tiles + 2 * ((NTILE + 1) & ~1)); // NE int2
  // rank[NE] aliases `side`: the CSR build completes before side is written.
  int*   rank = (int*)side;

  const dim3 blk(256);

  k_gather<<<dim3((3 * NB) / 4), blk, 0, stream>>>(embeds, users, pos, neg, out, 0);

  // CSR build
  hipMemsetAsync(base, 0, (size_t)(NN + 4) * sizeof(int), stream);
  k_count<<<dim3(4096), blk, 0, stream>>>(ei, base, rank);
  k_scan_part<<<dim3(NTILE), blk, 0, stream>>>(base, tiles);
  k_scan_tiles<<<dim3(1), dim3(128), 0, stream>>>(tiles, tiles + ((NTILE + 1) & ~1));
  k_scan_apply<<<dim3(NTILE), blk, 0, stream>>>(base, tiles + ((NTILE + 1) & ~1));
  k_permute<<<dim3(4096), blk, 0, stream>>>(ei, ew, base, rank, edata);

  const float* cur = embeds;
  for (int k = 0; k < 3; ++k) {
    k_aggregate<<<dim3(4096), blk, 0, stream>>>(cur, base, edata, side);
    k_update2<<<dim3((NN + 255) / 256), blk, 0, stream>>>(
        side, cur, ego,
        Wgc + (size_t)k * DD * DD, bgc + (size_t)k * DD,
        Wbi + (size_t)k * DD * DD, bbi + (size_t)k * DD);
    k_gather_norm<<<dim3((3 * NB) / 4), blk, 0, stream>>>(ego, users, pos, neg, out,
                                                          DD * (k + 1));
    cur = ego;
  }
}

// Round 11
// 565.129 us; speedup vs baseline: 4.9821x; 4.9821x over previous
//
#include <hip/hip_runtime.h>

#define NN 100000   // nodes
#define NE 1000000  // edges
#define DD 64       // dim
#define NB 4096     // batch
#define TILE 1024                       // scan tile (ints per block)
#define NTILE ((NN + TILE - 1) / TILE)  // 98

// ---------------------------------------------------------------------------
// CSR build step 1: count edges per destination AND record each edge's rank
// within its bucket (the atomic's return value). rank is stored coalesced.
// ---------------------------------------------------------------------------
__global__ __launch_bounds__(256) void k_count(
    const int* __restrict__ ei, int* __restrict__ base, int* __restrict__ rank)
{
  const int stride = gridDim.x * blockDim.x;
  for (int e = blockIdx.x * blockDim.x + threadIdx.x; e < NE; e += stride)
    rank[e] = atomicAdd(&base[ei[NE + e]], 1);
}

// ---------------------------------------------------------------------------
// Hierarchical exclusive scan of base[0..NN) (3 kernels, coalesced int4).
// ---------------------------------------------------------------------------
__global__ __launch_bounds__(256) void k_scan_part(
    const int* __restrict__ base, int* __restrict__ tilesum)
{
  __shared__ int s[256];
  const int t = threadIdx.x;
  const int i0 = blockIdx.x * TILE + t * 4;
  int4 v = make_int4(0, 0, 0, 0);
  if (i0 < NN) v = *reinterpret_cast<const int4*>(base + i0);  // NN%4==0
  s[t] = v.x + v.y + v.z + v.w;
  __syncthreads();
#pragma unroll
  for (int off = 128; off >= 1; off >>= 1) {
    if (t < off) s[t] += s[t + off];
    __syncthreads();
  }
  if (t == 0) tilesum[blockIdx.x] = s[0];
}

__global__ __launch_bounds__(128) void k_scan_tiles(
    const int* __restrict__ tilesum, int* __restrict__ tileoff)
{
  __shared__ int s[128];
  const int t = threadIdx.x;
  const int v = (t < NTILE) ? tilesum[t] : 0;
  s[t] = v;
  __syncthreads();
#pragma unroll
  for (int off = 1; off < 128; off <<= 1) {
    const int u = (t >= off) ? s[t - off] : 0;
    __syncthreads();
    s[t] += u;
    __syncthreads();
  }
  if (t < NTILE) tileoff[t] = s[t] - v;  // exclusive
}

__global__ __launch_bounds__(256) void k_scan_apply(
    int* __restrict__ base, const int* __restrict__ tileoff)
{
  __shared__ int s[256];
  const int t = threadIdx.x;
  const int i0 = blockIdx.x * TILE + t * 4;
  int4 v = make_int4(0, 0, 0, 0);
  if (i0 < NN) v = *reinterpret_cast<const int4*>(base + i0);
  const int sum = v.x + v.y + v.z + v.w;
  s[t] = sum;
  __syncthreads();
#pragma unroll
  for (int off = 1; off < 256; off <<= 1) {   // Hillis-Steele inclusive
    const int u = (t >= off) ? s[t - off] : 0;
    __syncthreads();
    s[t] += u;
    __syncthreads();
  }
  int p = s[t] - sum + tileoff[blockIdx.x];
  if (i0 < NN) {
    const int4 o = make_int4(p, p + v.x, p + v.x + v.y, p + v.x + v.y + v.z);
    *reinterpret_cast<int4*>(base + i0) = o;
  }
  if (blockIdx.x == 0 && t == 0) base[NN] = NE;
}

// ---------------------------------------------------------------------------
// CSR build step 3: bucket edges by destination, atomic-free.
// ---------------------------------------------------------------------------
__global__ __launch_bounds__(256) void k_permute(
    const int* __restrict__ ei, const float* __restrict__ ew,
    const int* __restrict__ base, const int* __restrict__ rank,
    int2* __restrict__ edata)
{
  const int stride = gridDim.x * blockDim.x;
  for (int e = blockIdx.x * blockDim.x + threadIdx.x; e < NE; e += stride) {
    const int c = ei[NE + e];
    const int slot = base[c] + rank[e];
    edata[slot] = make_int2(ei[e], __float_as_int(ew[e]));
  }
}

// ---------------------------------------------------------------------------
// Aggregation without atomics: one wave per node, lane = dim.
// ---------------------------------------------------------------------------
__global__ __launch_bounds__(256) void k_aggregate(
    const float* __restrict__ ego, const int* __restrict__ base,
    const int2* __restrict__ edata, float* __restrict__ side)
{
  const int lane = threadIdx.x & 63;
  const int gw = (blockIdx.x * 256 + threadIdx.x) >> 6;
  const int nw = (gridDim.x * 256) >> 6;
  for (int n = gw; n < NN; n += nw) {
    const int lo = base[n];
    const int hi = base[n + 1];
    float acc = 0.f;
    int j = lo;
    for (; j + 3 < hi; j += 4) {          // unroll-4 for load ILP
      const int2 a = edata[j];
      const int2 b = edata[j + 1];
      const int2 c = edata[j + 2];
      const int2 d = edata[j + 3];
      const float va = ego[(size_t)a.x * DD + lane];
      const float vb = ego[(size_t)b.x * DD + lane];
      const float vc = ego[(size_t)c.x * DD + lane];
      const float vd = ego[(size_t)d.x * DD + lane];
      acc = fmaf(va, __int_as_float(a.y), acc);
      acc = fmaf(vb, __int_as_float(b.y), acc);
      acc = fmaf(vc, __int_as_float(c.y), acc);
      acc = fmaf(vd, __int_as_float(d.y), acc);
    }
    for (; j < hi; ++j) {
      const int2 a = edata[j];
      acc = fmaf(ego[(size_t)a.x * DD + lane], __int_as_float(a.y), acc);
    }
    side[(size_t)n * DD + lane] = acc;
  }
}

// ---------------------------------------------------------------------------
// Dense update, thread-per-node, SPILL-PROOF layout (r9 lesson: keeping the
// whole 128-float row live spilled to scratch at VGPR=256 / 830 µs).
// Here: acc[64] (output row) stays live; side/ego stream through 16-element
// k-chunks. ~115 VGPR. W indices are wave-uniform -> s_load broadcast.
//   x = s@Wgc + p@Wbi + bias ; ego_out = leaky_relu(x, 0.2)
// ---------------------------------------------------------------------------
__global__ __launch_bounds__(256) void k_update3(
    const float* __restrict__ side, const float* __restrict__ ego_in,
    float* __restrict__ ego_out,
    const float* __restrict__ Wgc, const float* __restrict__ bgc,
    const float* __restrict__ Wbi, const float* __restrict__ bbi)
{
  const int n = blockIdx.x * 256 + threadIdx.x;
  const int nc = (n < NN) ? n : (NN - 1);   // clamp loads; guard stores
  const bool act = (n < NN);

  float acc[DD];
#pragma unroll
  for (int j = 0; j < DD; ++j) acc[j] = bgc[j] + bbi[j];  // uniform s_loads

#pragma unroll 1            // keep kt rolled: body ~2K fma, fits I$
  for (int kt = 0; kt < DD / 16; ++kt) {
    const float4* s4 = reinterpret_cast<const float4*>(
        side + (size_t)nc * DD + kt * 16);
    const float4* e4 = reinterpret_cast<const float4*>(
        ego_in + (size_t)nc * DD + kt * 16);
    float sc[16], pc[16];
#pragma unroll
    for (int q = 0; q < 4; ++q) {
      const float4 sv = s4[q];
      const float4 ev = e4[q];
      sc[4 * q + 0] = sv.x; sc[4 * q + 1] = sv.y;
      sc[4 * q + 2] = sv.z; sc[4 * q + 3] = sv.w;
      pc[4 * q + 0] = sv.x * ev.x; pc[4 * q + 1] = sv.y * ev.y;
      pc[4 * q + 2] = sv.z * ev.z; pc[4 * q + 3] = sv.w * ev.w;
    }
    const float* wg = Wgc + (size_t)kt * 16 * DD;  // uniform -> scalar loads
    const float* wb = Wbi + (size_t)kt * 16 * DD;
#pragma unroll
    for (int kk = 0; kk < 16; ++kk) {
      const float sk = sc[kk], pk = pc[kk];
#pragma unroll
      for (int j = 0; j < DD; ++j)
        acc[j] = fmaf(sk, wg[kk * DD + j], fmaf(pk, wb[kk * DD + j], acc[j]));
    }
  }

  if (act) {
    float4* orow = reinterpret_cast<float4*>(ego_out + (size_t)nc * DD);
#pragma unroll
    for (int q = 0; q < DD / 4; ++q) {
      const float a0 = acc[4 * q + 0], a1 = acc[4 * q + 1];
      const float a2 = acc[4 * q + 2], a3 = acc[4 * q + 3];
      float4 o;
      o.x = (a0 > 0.f) ? a0 : 0.2f * a0;
      o.y = (a1 > 0.f) ? a1 : 0.2f * a1;
      o.z = (a2 > 0.f) ? a2 : 0.2f * a2;
      o.w = (a3 > 0.f) ? a3 : 0.2f * a3;
      orow[q] = o;
    }
  }
}

// ---------------------------------------------------------------------------
// Plain gather (embeds block, no normalization).
// ---------------------------------------------------------------------------
__global__ __launch_bounds__(256) void k_gather(
    const float* __restrict__ src, const int* __restrict__ users,
    const int* __restrict__ pos, const int* __restrict__ neg,
    float* __restrict__ out, int colOff)
{
  const int w = (blockIdx.x * 256 + threadIdx.x) >> 6;
  const int lane = threadIdx.x & 63;
  if (w >= 3 * NB) return;
  const int t = w / NB;
  const int i = w - t * NB;
  const int* idxp = (t == 0) ? users : ((t == 1) ? pos : neg);
  const int idx = idxp[i];
  const float v = src[(size_t)idx * DD + lane];
  const size_t o = (size_t)w * 256 + colOff + lane;
  out[o] = v;
  out[o + (size_t)3 * NB * 256] = v;
}

// ---------------------------------------------------------------------------
// Normalizing gather: L2-normalize the sampled ego row on the fly.
// Only 12,288 of 100K rows are ever read normalized — skip the rest.
// ---------------------------------------------------------------------------
__global__ __launch_bounds__(256) void k_gather_norm(
    const float* __restrict__ src, const int* __restrict__ users,
    const int* __restrict__ pos, const int* __restrict__ neg,
    float* __restrict__ out, int colOff)
{
  const int w = (blockIdx.x * 256 + threadIdx.x) >> 6;
  const int lane = threadIdx.x & 63;
  if (w >= 3 * NB) return;
  const int t = w / NB;
  const int i = w - t * NB;
  const int* idxp = (t == 0) ? users : ((t == 1) ? pos : neg);
  const int idx = idxp[i];
  const float v = src[(size_t)idx * DD + lane];
  float ss = v * v;
#pragma unroll
  for (int off = 32; off >= 1; off >>= 1) ss += __shfl_xor(ss, off);
  const float nrm = fmaxf(sqrtf(ss), 1e-12f);
  const float nv = v / nrm;
  const size_t o = (size_t)w * 256 + colOff + lane;
  out[o] = nv;
  out[o + (size_t)3 * NB * 256] = nv;
}

extern "C" void kernel_launch(void* const* d_in, const int* in_sizes, int n_in,
                              void* d_out, int out_size, void* d_ws, size_t ws_size,
                              hipStream_t stream)
{
  const float* embeds = (const float*)d_in[0];
  const float* ew     = (const float*)d_in[1];
  const float* Wgc    = (const float*)d_in[2];
  const float* bgc    = (const float*)d_in[3];
  const float* Wbi    = (const float*)d_in[4];
  const float* bbi    = (const float*)d_in[5];
  const int*   ei     = (const int*)d_in[6];
  const int*   users  = (const int*)d_in[7];
  const int*   pos    = (const int*)d_in[8];
  const int*   neg    = (const int*)d_in[9];
  float* out = (float*)d_out;

  // Workspace layout (4B units); 16B alignment holds for all accesses.
  float* side = (float*)d_ws;                     // NN*DD
  float* ego  = side + (size_t)NN * DD;           // NN*DD
  int*   base   = (int*)(ego + (size_t)NN * DD);  // NN+4 (pad)
  int*   tiles  = base + (NN + 4);                // NTILE sums + NTILE offs
  int2*  edata  = (int2*)(tiles + 2 * ((NTILE + 1) & ~1)); // NE int2
  // rank[NE] aliases `side`: the CSR build completes before side is written.
  int*   rank = (int*)side;

  const dim3 blk(256);

  k_gather<<<dim3((3 * NB) / 4), blk, 0, stream>>>(embeds, users, pos, neg, out, 0);

  // CSR build
  hipMemsetAsync(base, 0, (size_t)(NN + 4) * sizeof(int), stream);
  k_count<<<dim3(4096), blk, 0, stream>>>(ei, base, rank);
  k_scan_part<<<dim3(NTILE), blk, 0, stream>>>(base, tiles);
  k_scan_tiles<<<dim3(1), dim3(128), 0, stream>>>(tiles, tiles + ((NTILE + 1) & ~1));
  k_scan_apply<<<dim3(NTILE), blk, 0, stream>>>(base, tiles + ((NTILE + 1) & ~1));
  k_permute<<<dim3(4096), blk, 0, stream>>>(ei, ew, base, rank, edata);

  const float* cur = embeds;
  for (int k = 0; k < 3; ++k) {
    k_aggregate<<<dim3(4096), blk, 0, stream>>>(cur, base, edata, side);
    k_update3<<<dim3((NN + 255) / 256), blk, 0, stream>>>(
        side, cur, ego,
        Wgc + (size_t)k * DD * DD, bgc + (size_t)k * DD,
        Wbi + (size_t)k * DD * DD, bbi + (size_t)k * DD);
    k_gather_norm<<<dim3((3 * NB) / 4), blk, 0, stream>>>(ego, users, pos, neg, out,
                                                          DD * (k + 1));
    cur = ego;
  }
}

// Round 12
// 516.819 us; speedup vs baseline: 5.4478x; 1.0935x over previous
//
#include <hip/hip_runtime.h>

#define NN 100000   // nodes
#define NE 1000000  // edges
#define DD 64       // dim
#define NB 4096     // batch
#define TILE 1024                       // scan tile (ints per block)
#define NTILE ((NN + TILE - 1) / TILE)  // 98

// ---------------------------------------------------------------------------
// CSR build step 1: count edges per destination AND record each edge's rank
// within its bucket (the atomic's return value). rank is stored coalesced.
// ---------------------------------------------------------------------------
__global__ __launch_bounds__(256) void k_count(
    const int* __restrict__ ei, int* __restrict__ base, int* __restrict__ rank)
{
  const int stride = gridDim.x * blockDim.x;
  for (int e = blockIdx.x * blockDim.x + threadIdx.x; e < NE; e += stride)
    rank[e] = atomicAdd(&base[ei[NE + e]], 1);
}

// ---------------------------------------------------------------------------
// Hierarchical exclusive scan of base[0..NN) (3 kernels, coalesced int4).
// ---------------------------------------------------------------------------
__global__ __launch_bounds__(256) void k_scan_part(
    const int* __restrict__ base, int* __restrict__ tilesum)
{
  __shared__ int s[256];
  const int t = threadIdx.x;
  const int i0 = blockIdx.x * TILE + t * 4;
  int4 v = make_int4(0, 0, 0, 0);
  if (i0 < NN) v = *reinterpret_cast<const int4*>(base + i0);  // NN%4==0
  s[t] = v.x + v.y + v.z + v.w;
  __syncthreads();
#pragma unroll
  for (int off = 128; off >= 1; off >>= 1) {
    if (t < off) s[t] += s[t + off];
    __syncthreads();
  }
  if (t == 0) tilesum[blockIdx.x] = s[0];
}

__global__ __launch_bounds__(128) void k_scan_tiles(
    const int* __restrict__ tilesum, int* __restrict__ tileoff)
{
  __shared__ int s[128];
  const int t = threadIdx.x;
  const int v = (t < NTILE) ? tilesum[t] : 0;
  s[t] = v;
  __syncthreads();
#pragma unroll
  for (int off = 1; off < 128; off <<= 1) {
    const int u = (t >= off) ? s[t - off] : 0;
    __syncthreads();
    s[t] += u;
    __syncthreads();
  }
  if (t < NTILE) tileoff[t] = s[t] - v;  // exclusive
}

__global__ __launch_bounds__(256) void k_scan_apply(
    int* __restrict__ base, const int* __restrict__ tileoff)
{
  __shared__ int s[256];
  const int t = threadIdx.x;
  const int i0 = blockIdx.x * TILE + t * 4;
  int4 v = make_int4(0, 0, 0, 0);
  if (i0 < NN) v = *reinterpret_cast<const int4*>(base + i0);
  const int sum = v.x + v.y + v.z + v.w;
  s[t] = sum;
  __syncthreads();
#pragma unroll
  for (int off = 1; off < 256; off <<= 1) {   // Hillis-Steele inclusive
    const int u = (t >= off) ? s[t - off] : 0;
    __syncthreads();
    s[t] += u;
    __syncthreads();
  }
  int p = s[t] - sum + tileoff[blockIdx.x];
  if (i0 < NN) {
    const int4 o = make_int4(p, p + v.x, p + v.x + v.y, p + v.x + v.y + v.z);
    *reinterpret_cast<int4*>(base + i0) = o;
  }
  if (blockIdx.x == 0 && t == 0) base[NN] = NE;
}

// ---------------------------------------------------------------------------
// CSR build step 3: bucket edges by destination, atomic-free.
// ---------------------------------------------------------------------------
__global__ __launch_bounds__(256) void k_permute(
    const int* __restrict__ ei, const float* __restrict__ ew,
    const int* __restrict__ base, const int* __restrict__ rank,
    int2* __restrict__ edata)
{
  const int stride = gridDim.x * blockDim.x;
  for (int e = blockIdx.x * blockDim.x + threadIdx.x; e < NE; e += stride) {
    const int c = ei[NE + e];
    const int slot = base[c] + rank[e];
    edata[slot] = make_int2(ei[e], __float_as_int(ew[e]));
  }
}

// ---------------------------------------------------------------------------
// Aggregation + fused hadamard: one wave per node, lane = dim.
//   side[n,:] = sum over incident edges of ego[row]*w
//   prod[n,:] = side[n,:] * ego[n,:]     (pre-computed for k_update4's
//               scalar-broadcast path — no scalar float mul exists)
// ---------------------------------------------------------------------------
__global__ __launch_bounds__(256) void k_aggregate2(
    const float* __restrict__ ego, const int* __restrict__ base,
    const int2* __restrict__ edata, float* __restrict__ side,
    float* __restrict__ prod)
{
  const int lane = threadIdx.x & 63;
  const int gw = (blockIdx.x * 256 + threadIdx.x) >> 6;
  const int nw = (gridDim.x * 256) >> 6;
  for (int n = gw; n < NN; n += nw) {
    const int lo = base[n];
    const int hi = base[n + 1];
    const float eg = ego[(size_t)n * DD + lane];  // own row, coalesced
    float acc = 0.f;
    int j = lo;
    for (; j + 3 < hi; j += 4) {          // unroll-4 for load ILP
      const int2 a = edata[j];
      const int2 b = edata[j + 1];
      const int2 c = edata[j + 2];
      const int2 d = edata[j + 3];
      const float va = ego[(size_t)a.x * DD + lane];
      const float vb = ego[(size_t)b.x * DD + lane];
      const float vc = ego[(size_t)c.x * DD + lane];
      const float vd = ego[(size_t)d.x * DD + lane];
      acc = fmaf(va, __int_as_float(a.y), acc);
      acc = fmaf(vb, __int_as_float(b.y), acc);
      acc = fmaf(vc, __int_as_float(c.y), acc);
      acc = fmaf(vd, __int_as_float(d.y), acc);
    }
    for (; j < hi; ++j) {
      const int2 a = edata[j];
      acc = fmaf(ego[(size_t)a.x * DD + lane], __int_as_float(a.y), acc);
    }
    side[(size_t)n * DD + lane] = acc;
    prod[(size_t)n * DD + lane] = acc * eg;
  }
}

// ---------------------------------------------------------------------------
// Dense update v4: wave per node (lane = output dim), rows broadcast via the
// SCALAR path. r7 burned 128 v_readlane/node; r11's thread-per-node wrecked
// the access pattern (2x over-fetch, FETCH=101MB, VALUBusy 9.7%). Here the
// row pointer is wave-uniform (readfirstlane) so srow[j]/prow[j] are uniform
// loads -> s_load; each j is one v_fmac with an SGPR operand. W columns live
// in VGPRs (lane d holds W[:,d]), loaded once per wave, amortized by
// grid-stride. ~128 fmac + ~8 s_load per node.
// ---------------------------------------------------------------------------
__global__ __launch_bounds__(256) void k_update4(
    const float* __restrict__ side, const float* __restrict__ prod,
    float* __restrict__ ego_out,
    const float* __restrict__ Wgc, const float* __restrict__ bgc,
    const float* __restrict__ Wbi, const float* __restrict__ bbi)
{
  const int lane = threadIdx.x & 63;
  float wg[DD], wb[DD];
#pragma unroll
  for (int j = 0; j < DD; ++j) {
    wg[j] = Wgc[j * DD + lane];   // coalesced row reads; lane d keeps W[:,d]
    wb[j] = Wbi[j * DD + lane];
  }
  const float bias = bgc[lane] + bbi[lane];
  const int gw = (blockIdx.x * 256 + threadIdx.x) >> 6;
  const int nw = (gridDim.x * 256) >> 6;
#pragma unroll 1
  for (int n = gw; n < NN; n += nw) {
    const int nu = __builtin_amdgcn_readfirstlane(n);  // wave-uniform row id
    const float* __restrict__ srow = side + (size_t)nu * DD;
    const float* __restrict__ prow = prod + (size_t)nu * DD;
    float acc = bias;
#pragma unroll
    for (int j = 0; j < DD; ++j) {
      acc = fmaf(srow[j], wg[j], acc);   // s_load + v_fmac (sgpr operand)
      acc = fmaf(prow[j], wb[j], acc);
    }
    const float x = (acc > 0.f) ? acc : 0.2f * acc;   // leaky_relu(0.2)
    ego_out[(size_t)nu * DD + lane] = x;
  }
}

// ---------------------------------------------------------------------------
// Plain gather (embeds block, no normalization).
// ---------------------------------------------------------------------------
__global__ __launch_bounds__(256) void k_gather(
    const float* __restrict__ src, const int* __restrict__ users,
    const int* __restrict__ pos, const int* __restrict__ neg,
    float* __restrict__ out, int colOff)
{
  const int w = (blockIdx.x * 256 + threadIdx.x) >> 6;
  const int lane = threadIdx.x & 63;
  if (w >= 3 * NB) return;
  const int t = w / NB;
  const int i = w - t * NB;
  const int* idxp = (t == 0) ? users : ((t == 1) ? pos : neg);
  const int idx = idxp[i];
  const float v = src[(size_t)idx * DD + lane];
  const size_t o = (size_t)w * 256 + colOff + lane;
  out[o] = v;
  out[o + (size_t)3 * NB * 256] = v;
}

// ---------------------------------------------------------------------------
// Normalizing gather: L2-normalize the sampled ego row on the fly.
// Only 12,288 of 100K rows are ever read normalized — skip the rest.
// ---------------------------------------------------------------------------
__global__ __launch_bounds__(256) void k_gather_norm(
    const float* __restrict__ src, const int* __restrict__ users,
    const int* __restrict__ pos, const int* __restrict__ neg,
    float* __restrict__ out, int colOff)
{
  const int w = (blockIdx.x * 256 + threadIdx.x) >> 6;
  const int lane = threadIdx.x & 63;
  if (w >= 3 * NB) return;
  const int t = w / NB;
  const int i = w - t * NB;
  const int* idxp = (t == 0) ? users : ((t == 1) ? pos : neg);
  const int idx = idxp[i];
  const float v = src[(size_t)idx * DD + lane];
  float ss = v * v;
#pragma unroll
  for (int off = 32; off >= 1; off >>= 1) ss += __shfl_xor(ss, off);
  const float nrm = fmaxf(sqrtf(ss), 1e-12f);
  const float nv = v / nrm;
  const size_t o = (size_t)w * 256 + colOff + lane;
  out[o] = nv;
  out[o + (size_t)3 * NB * 256] = nv;
}

extern "C" void kernel_launch(void* const* d_in, const int* in_sizes, int n_in,
                              void* d_out, int out_size, void* d_ws, size_t ws_size,
                              hipStream_t stream)
{
  const float* embeds = (const float*)d_in[0];
  const float* ew     = (const float*)d_in[1];
  const float* Wgc    = (const float*)d_in[2];
  const float* bgc    = (const float*)d_in[3];
  const float* Wbi    = (const float*)d_in[4];
  const float* bbi    = (const float*)d_in[5];
  const int*   ei     = (const int*)d_in[6];
  const int*   users  = (const int*)d_in[7];
  const int*   pos    = (const int*)d_in[8];
  const int*   neg    = (const int*)d_in[9];
  float* out = (float*)d_out;

  // Workspace layout (4B units); 16B alignment holds for all accesses.
  float* side = (float*)d_ws;                     // NN*DD
  float* ego  = side + (size_t)NN * DD;           // NN*DD
  float* prod = ego  + (size_t)NN * DD;           // NN*DD
  int*   base   = (int*)(prod + (size_t)NN * DD); // NN+4 (pad)
  int*   tiles  = base + (NN + 4);                // NTILE sums + NTILE offs
  int2*  edata  = (int2*)(tiles + 2 * ((NTILE + 1) & ~1)); // NE int2
  // rank[NE] aliases `side`: the CSR build completes before side is written.
  int*   rank = (int*)side;

  const dim3 blk(256);

  k_gather<<<dim3((3 * NB) / 4), blk, 0, stream>>>(embeds, users, pos, neg, out, 0);

  // CSR build
  hipMemsetAsync(base, 0, (size_t)(NN + 4) * sizeof(int), stream);
  k_count<<<dim3(4096), blk, 0, stream>>>(ei, base, rank);
  k_scan_part<<<dim3(NTILE), blk, 0, stream>>>(base, tiles);
  k_scan_tiles<<<dim3(1), dim3(128), 0, stream>>>(tiles, tiles + ((NTILE + 1) & ~1));
  k_scan_apply<<<dim3(NTILE), blk, 0, stream>>>(base, tiles + ((NTILE + 1) & ~1));
  k_permute<<<dim3(4096), blk, 0, stream>>>(ei, ew, base, rank, edata);

  const float* cur = embeds;
  for (int k = 0; k < 3; ++k) {
    k_aggregate2<<<dim3(4096), blk, 0, stream>>>(cur, base, edata, side, prod);
    k_update4<<<dim3(1024), blk, 0, stream>>>(
        side, prod, ego,
        Wgc + (size_t)k * DD * DD, bgc + (size_t)k * DD,
        Wbi + (size_t)k * DD * DD, bbi + (size_t)k * DD);
    k_gather_norm<<<dim3((3 * NB) / 4), blk, 0, stream>>>(ego, users, pos, neg, out,
                                                          DD * (k + 1));
    cur = ego;
  }
}